// Round 1
// baseline (895.823 us; speedup 1.0000x reference)
//
#include <hip/hip_runtime.h>

#define NN   50000
#define NE   800000
#define F_IN 128
#define F_H  128
#define F_O  64

static constexpr int NB_NODE = (NN + 255) / 256;   // 196 blocks over nodes
static constexpr int NB_EDGE = (NE + 255) / 256;   // 3125 blocks over edges

// ---------------------------------------------------------------------------
// Edge normalization: detect int32 vs int64 storage, emit int32 src/dst.
// int64 little-endian => odd int32 words of the first elements are 0 (all
// indices < 50000). Probability of false positive with int32 data ~ (2e-5)^4.
// ---------------------------------------------------------------------------
__global__ __launch_bounds__(256) void k_norm_edges(const int* __restrict__ ei32,
                                                    int* __restrict__ src,
                                                    int* __restrict__ dst) {
    int e = blockIdx.x * 256 + threadIdx.x;
    if (e >= NE) return;
    bool is64 = ((ei32[1] | ei32[3] | ei32[5] | ei32[7]) == 0);
    if (is64) {
        const long long* ei64 = (const long long*)ei32;
        src[e] = (int)ei64[e];
        dst[e] = (int)ei64[NE + e];
    } else {
        src[e] = ei32[e];
        dst[e] = ei32[NE + e];
    }
}

// ---------------------------------------------------------------------------
// CSR build: count in-degrees, 3-kernel exclusive scan, scatter src indices.
// ---------------------------------------------------------------------------
__global__ __launch_bounds__(256) void k_count(const int* __restrict__ dst,
                                               unsigned* __restrict__ cnt) {
    int e = blockIdx.x * 256 + threadIdx.x;
    if (e < NE) atomicAdd(&cnt[dst[e]], 1u);
}

__global__ __launch_bounds__(256) void k_blocksum(const unsigned* __restrict__ cnt,
                                                  unsigned* __restrict__ bsum) {
    __shared__ unsigned s[256];
    int i = blockIdx.x * 256 + threadIdx.x;
    unsigned v = (i < NN) ? cnt[i] : 0u;
    s[threadIdx.x] = v;
    __syncthreads();
    for (int off = 128; off > 0; off >>= 1) {
        if (threadIdx.x < off) s[threadIdx.x] += s[threadIdx.x + off];
        __syncthreads();
    }
    if (threadIdx.x == 0) bsum[blockIdx.x] = s[0];
}

__global__ __launch_bounds__(256) void k_scan_bsums(const unsigned* __restrict__ bsum,
                                                    unsigned* __restrict__ bscan) {
    __shared__ unsigned s[256];
    unsigned v = (threadIdx.x < NB_NODE) ? bsum[threadIdx.x] : 0u;
    s[threadIdx.x] = v;
    __syncthreads();
    for (int off = 1; off < 256; off <<= 1) {
        unsigned t = (threadIdx.x >= (unsigned)off) ? s[threadIdx.x - off] : 0u;
        __syncthreads();
        s[threadIdx.x] += t;
        __syncthreads();
    }
    if (threadIdx.x < NB_NODE) bscan[threadIdx.x] = s[threadIdx.x] - v;  // exclusive
}

__global__ __launch_bounds__(256) void k_scan_local(const unsigned* __restrict__ cnt,
                                                    const unsigned* __restrict__ bscan,
                                                    unsigned* __restrict__ row_ptr,
                                                    unsigned* __restrict__ cursor,
                                                    float* __restrict__ dinv) {
    __shared__ unsigned s[256];
    int i = blockIdx.x * 256 + threadIdx.x;
    unsigned v = (i < NN) ? cnt[i] : 0u;
    s[threadIdx.x] = v;
    __syncthreads();
    for (int off = 1; off < 256; off <<= 1) {
        unsigned t = (threadIdx.x >= (unsigned)off) ? s[threadIdx.x - off] : 0u;
        __syncthreads();
        s[threadIdx.x] += t;
        __syncthreads();
    }
    if (i < NN) {
        unsigned ex = bscan[blockIdx.x] + s[threadIdx.x] - v;  // exclusive prefix
        row_ptr[i] = ex;
        cursor[i]  = ex;
        dinv[i]    = 1.0f / sqrtf((float)(v + 1u));  // +1 self-loop
    }
    if (i == 0) row_ptr[NN] = NE;
}

__global__ __launch_bounds__(256) void k_scatter(const int* __restrict__ src,
                                                 const int* __restrict__ dst,
                                                 unsigned* __restrict__ cursor,
                                                 int* __restrict__ srcs) {
    int e = blockIdx.x * 256 + threadIdx.x;
    if (e < NE) {
        unsigned p = atomicAdd(&cursor[dst[e]], 1u);
        srcs[p] = src[e];
    }
}

// ---------------------------------------------------------------------------
// f32 GEMM  Y[r][c] = dinv[r] * sum_k X[r][k] * W[k][c]
// 64 rows/block, W staged in KC-row chunks (32KB) + X tile (32KB) in LDS.
// ---------------------------------------------------------------------------
template <int K, int NOUT, int KC>
__global__ __launch_bounds__(256, 2) void k_gemm_scaled(const float* __restrict__ X,
                                                        const float* __restrict__ W,
                                                        const float* __restrict__ dinv,
                                                        float* __restrict__ Y) {
    constexpr int CX  = NOUT / 4;   // col quads per row of threads
    constexpr int CY  = 256 / CX;
    constexpr int RPT = 64 / CY;    // rows per thread
    __shared__ float4 sX[64 * (K / 4)];
    __shared__ float4 sW[KC * (NOUT / 4)];

    const int t  = threadIdx.x;
    const int r0 = blockIdx.x * 64;

    for (int i = t; i < 64 * (K / 4); i += 256) {
        int r = i / (K / 4), c = i % (K / 4);
        int gr = r0 + r;
        sX[i] = (gr < NN) ? ((const float4*)X)[(size_t)gr * (K / 4) + c]
                          : make_float4(0.f, 0.f, 0.f, 0.f);
    }

    const int tx = t % CX;
    const int ty = t / CX;
    float4 acc[RPT];
#pragma unroll
    for (int r = 0; r < RPT; ++r) acc[r] = make_float4(0.f, 0.f, 0.f, 0.f);

    for (int kc = 0; kc < K; kc += KC) {
        __syncthreads();
        for (int i = t; i < KC * (NOUT / 4); i += 256)
            sW[i] = ((const float4*)W)[(size_t)kc * (NOUT / 4) + i];
        __syncthreads();
#pragma unroll
        for (int kk = 0; kk < KC / 4; ++kk) {
            float4 w0 = sW[(kk * 4 + 0) * (NOUT / 4) + tx];
            float4 w1 = sW[(kk * 4 + 1) * (NOUT / 4) + tx];
            float4 w2 = sW[(kk * 4 + 2) * (NOUT / 4) + tx];
            float4 w3 = sW[(kk * 4 + 3) * (NOUT / 4) + tx];
#pragma unroll
            for (int r = 0; r < RPT; ++r) {
                float4 xv = sX[(ty * RPT + r) * (K / 4) + (kc / 4 + kk)];
                acc[r].x += xv.x * w0.x + xv.y * w1.x + xv.z * w2.x + xv.w * w3.x;
                acc[r].y += xv.x * w0.y + xv.y * w1.y + xv.z * w2.y + xv.w * w3.y;
                acc[r].z += xv.x * w0.z + xv.y * w1.z + xv.z * w2.z + xv.w * w3.z;
                acc[r].w += xv.x * w0.w + xv.y * w1.w + xv.z * w2.w + xv.w * w3.w;
            }
        }
    }

#pragma unroll
    for (int r = 0; r < RPT; ++r) {
        int gr = r0 + ty * RPT + r;
        if (gr < NN) {
            float s = dinv[gr];
            float4 v = acc[r];
            v.x *= s; v.y *= s; v.z *= s; v.w *= s;
            ((float4*)Y)[(size_t)gr * (NOUT / 4) + tx] = v;
        }
    }
}

// ---------------------------------------------------------------------------
// Aggregation, one wave per node.
// Layer 1 (F=128): lane holds float2 (feats 2l, 2l+1). relu(dinv*sum + b).
// ---------------------------------------------------------------------------
__global__ __launch_bounds__(256) void k_agg1(const float* __restrict__ Xw,
                                              const int* __restrict__ srcs,
                                              const unsigned* __restrict__ row_ptr,
                                              const float* __restrict__ dinv,
                                              const float* __restrict__ b1,
                                              float* __restrict__ H) {
    int wv   = (blockIdx.x * 256 + threadIdx.x) >> 6;
    int lane = threadIdx.x & 63;
    if (wv >= NN) return;
    const float2* X2 = (const float2*)Xw;
    float2 ac = X2[(size_t)wv * 64 + lane];  // self-loop term (pre-scaled)
    unsigned i  = row_ptr[wv];
    unsigned ie = row_ptr[wv + 1];
    for (; i + 1 < ie; i += 2) {
        int s0 = srcs[i], s1 = srcs[i + 1];
        float2 v0 = X2[(size_t)s0 * 64 + lane];
        float2 v1 = X2[(size_t)s1 * 64 + lane];
        ac.x += v0.x + v1.x;
        ac.y += v0.y + v1.y;
    }
    if (i < ie) {
        float2 v = X2[(size_t)srcs[i] * 64 + lane];
        ac.x += v.x;
        ac.y += v.y;
    }
    float dn = dinv[wv];
    float o0 = dn * ac.x + b1[2 * lane];
    float o1 = dn * ac.y + b1[2 * lane + 1];
    ((float2*)H)[(size_t)wv * 64 + lane] = make_float2(fmaxf(o0, 0.f), fmaxf(o1, 0.f));
}

// Layer 2 (F=64): lane holds 1 float. dinv*sum + b (no relu).
__global__ __launch_bounds__(256) void k_agg2(const float* __restrict__ Hw,
                                              const int* __restrict__ srcs,
                                              const unsigned* __restrict__ row_ptr,
                                              const float* __restrict__ dinv,
                                              const float* __restrict__ b2,
                                              float* __restrict__ out) {
    int wv   = (blockIdx.x * 256 + threadIdx.x) >> 6;
    int lane = threadIdx.x & 63;
    if (wv >= NN) return;
    float ac = Hw[(size_t)wv * 64 + lane];  // self-loop
    unsigned i  = row_ptr[wv];
    unsigned ie = row_ptr[wv + 1];
    for (; i + 1 < ie; i += 2) {
        int s0 = srcs[i], s1 = srcs[i + 1];
        float v0 = Hw[(size_t)s0 * 64 + lane];
        float v1 = Hw[(size_t)s1 * 64 + lane];
        ac += v0 + v1;
    }
    if (i < ie) ac += Hw[(size_t)srcs[i] * 64 + lane];
    out[(size_t)wv * 64 + lane] = dinv[wv] * ac + b2[lane];
}

// ---------------------------------------------------------------------------
extern "C" void kernel_launch(void* const* d_in, const int* in_sizes, int n_in,
                              void* d_out, int out_size, void* d_ws, size_t ws_size,
                              hipStream_t stream) {
    const float* x  = (const float*)d_in[0];
    const int*   ei = (const int*)d_in[1];
    const float* W1 = (const float*)d_in[2];
    const float* b1 = (const float*)d_in[3];
    const float* W2 = (const float*)d_in[4];
    const float* b2 = (const float*)d_in[5];
    float* out = (float*)d_out;

    char* w = (char*)d_ws;
    size_t off = 0;
    auto alloc = [&](size_t bytes) {
        void* p = w + off;
        off += (bytes + 255) & ~(size_t)255;
        return p;
    };
    int*      srcN    = (int*)alloc((size_t)NE * 4);
    int*      dstN    = (int*)alloc((size_t)NE * 4);
    unsigned* cnt     = (unsigned*)alloc((size_t)NN * 4);
    unsigned* row_ptr = (unsigned*)alloc((size_t)(NN + 1) * 4);
    unsigned* cursor  = (unsigned*)alloc((size_t)NN * 4);
    float*    dinv    = (float*)alloc((size_t)NN * 4);
    unsigned* bsum    = (unsigned*)alloc(256 * 4);
    unsigned* bscan   = (unsigned*)alloc(256 * 4);
    int*      srcs    = (int*)alloc((size_t)NE * 4);
    float*    Xw      = (float*)alloc((size_t)NN * F_H * 4);   // also reused as Hw
    float*    H1      = (float*)alloc((size_t)NN * F_H * 4);
    float*    Hw      = Xw;  // alias: Xw dead after k_agg1

    // CSR build
    k_norm_edges<<<NB_EDGE, 256, 0, stream>>>(ei, srcN, dstN);
    hipMemsetAsync(cnt, 0, (size_t)NN * 4, stream);
    k_count<<<NB_EDGE, 256, 0, stream>>>(dstN, cnt);
    k_blocksum<<<NB_NODE, 256, 0, stream>>>(cnt, bsum);
    k_scan_bsums<<<1, 256, 0, stream>>>(bsum, bscan);
    k_scan_local<<<NB_NODE, 256, 0, stream>>>(cnt, bscan, row_ptr, cursor, dinv);
    k_scatter<<<NB_EDGE, 256, 0, stream>>>(srcN, dstN, cursor, srcs);

    // Layer 1: Xw = dinv * (x @ W1); H1 = relu(dinv * agg(Xw) + b1)
    k_gemm_scaled<F_IN, F_H, 64><<<(NN + 63) / 64, 256, 0, stream>>>(x, W1, dinv, Xw);
    k_agg1<<<(NN + 3) / 4, 256, 0, stream>>>(Xw, srcs, row_ptr, dinv, b1, H1);

    // Layer 2: Hw = dinv * (H1 @ W2); out = dinv * agg(Hw) + b2
    k_gemm_scaled<F_H, F_O, 128><<<(NN + 63) / 64, 256, 0, stream>>>(H1, W2, dinv, Hw);
    k_agg2<<<(NN + 3) / 4, 256, 0, stream>>>(Hw, srcs, row_ptr, dinv, b2, out);
}

// Round 2
// 315.909 us; speedup vs baseline: 2.8357x; 2.8357x over previous
//
#include <hip/hip_runtime.h>
#include <hip/hip_bf16.h>

#define NN   50000
#define NE   800000
#define F_IN 128
#define F_H  128
#define F_O  64

static constexpr int NB_NODE = (NN + 255) / 256;   // 196 blocks over nodes
static constexpr int NB_EDGE = (NE + 255) / 256;   // 3125 blocks over edges

typedef __bf16 bf16_8 __attribute__((ext_vector_type(8)));
typedef float  f32x4  __attribute__((ext_vector_type(4)));

// ---------------------------------------------------------------------------
// Edge normalization: detect int32 vs int64 storage, emit int32 src/dst.
// ---------------------------------------------------------------------------
__global__ __launch_bounds__(256) void k_norm_edges(const int* __restrict__ ei32,
                                                    int* __restrict__ src,
                                                    int* __restrict__ dst) {
    int e = blockIdx.x * 256 + threadIdx.x;
    if (e >= NE) return;
    bool is64 = ((ei32[1] | ei32[3] | ei32[5] | ei32[7]) == 0);
    if (is64) {
        const long long* ei64 = (const long long*)ei32;
        src[e] = (int)ei64[e];
        dst[e] = (int)ei64[NE + e];
    } else {
        src[e] = ei32[e];
        dst[e] = ei32[NE + e];
    }
}

// ---------------------------------------------------------------------------
// CSR build: count in-degrees, 3-kernel exclusive scan, scatter src indices.
// ---------------------------------------------------------------------------
__global__ __launch_bounds__(256) void k_count(const int* __restrict__ dst,
                                               unsigned* __restrict__ cnt) {
    int e = blockIdx.x * 256 + threadIdx.x;
    if (e < NE) atomicAdd(&cnt[dst[e]], 1u);
}

__global__ __launch_bounds__(256) void k_blocksum(const unsigned* __restrict__ cnt,
                                                  unsigned* __restrict__ bsum) {
    __shared__ unsigned s[256];
    int i = blockIdx.x * 256 + threadIdx.x;
    unsigned v = (i < NN) ? cnt[i] : 0u;
    s[threadIdx.x] = v;
    __syncthreads();
    for (int off = 128; off > 0; off >>= 1) {
        if (threadIdx.x < off) s[threadIdx.x] += s[threadIdx.x + off];
        __syncthreads();
    }
    if (threadIdx.x == 0) bsum[blockIdx.x] = s[0];
}

__global__ __launch_bounds__(256) void k_scan_bsums(const unsigned* __restrict__ bsum,
                                                    unsigned* __restrict__ bscan) {
    __shared__ unsigned s[256];
    unsigned v = (threadIdx.x < NB_NODE) ? bsum[threadIdx.x] : 0u;
    s[threadIdx.x] = v;
    __syncthreads();
    for (int off = 1; off < 256; off <<= 1) {
        unsigned t = (threadIdx.x >= (unsigned)off) ? s[threadIdx.x - off] : 0u;
        __syncthreads();
        s[threadIdx.x] += t;
        __syncthreads();
    }
    if (threadIdx.x < NB_NODE) bscan[threadIdx.x] = s[threadIdx.x] - v;  // exclusive
}

__global__ __launch_bounds__(256) void k_scan_local(const unsigned* __restrict__ cnt,
                                                    const unsigned* __restrict__ bscan,
                                                    unsigned* __restrict__ row_ptr,
                                                    unsigned* __restrict__ cursor,
                                                    float* __restrict__ dinv) {
    __shared__ unsigned s[256];
    int i = blockIdx.x * 256 + threadIdx.x;
    unsigned v = (i < NN) ? cnt[i] : 0u;
    s[threadIdx.x] = v;
    __syncthreads();
    for (int off = 1; off < 256; off <<= 1) {
        unsigned t = (threadIdx.x >= (unsigned)off) ? s[threadIdx.x - off] : 0u;
        __syncthreads();
        s[threadIdx.x] += t;
        __syncthreads();
    }
    if (i < NN) {
        unsigned ex = bscan[blockIdx.x] + s[threadIdx.x] - v;  // exclusive prefix
        row_ptr[i] = ex;
        cursor[i]  = ex;
        dinv[i]    = 1.0f / sqrtf((float)(v + 1u));  // +1 self-loop
    }
    if (i == 0) row_ptr[NN] = NE;
}

__global__ __launch_bounds__(256) void k_scatter(const int* __restrict__ src,
                                                 const int* __restrict__ dst,
                                                 unsigned* __restrict__ cursor,
                                                 int* __restrict__ srcs) {
    int e = blockIdx.x * 256 + threadIdx.x;
    if (e < NE) {
        unsigned p = atomicAdd(&cursor[dst[e]], 1u);
        srcs[p] = src[e];
    }
}

// ---------------------------------------------------------------------------
// bf16 MFMA GEMM:  Y_bf16[r][c] = dinv[r] * sum_k A[r][k] * W[k][c]
// Block = 64 rows (4 waves x 16 rows). W (f32, KxNOUT row-major) staged once
// into LDS pre-swizzled to B-fragment layout [ks][c][n][q][j] so each lane's
// fragment is one 16B ds_read. A-fragments loaded straight from global.
// mfma_f32_16x16x32_bf16: A[m=lane&15][k=(lane>>4)*8+j],
//                         B[k=(lane>>4)*8+j][n=lane&15],
//                         D[row=(lane>>4)*4+reg][col=lane&15].
// ---------------------------------------------------------------------------
template <typename AT, int K, int NOUT>
__global__ __launch_bounds__(256) void k_gemm_mfma(const AT* __restrict__ X,
                                                   const float* __restrict__ W,
                                                   const float* __restrict__ dinv,
                                                   __hip_bfloat16* __restrict__ Y) {
    constexpr int NKS = K / 32;     // K-steps
    constexpr int NC  = NOUT / 16;  // column tiles
    __shared__ __hip_bfloat16 WB[NKS * NC * 16 * 4 * 8];

    const int t = threadIdx.x;
    for (int f = t; f < K * NOUT; f += 256) {
        int k = f / NOUT, n = f % NOUT;
        int ks = k >> 5, kr = k & 31, qq = kr >> 3, jj = kr & 7;
        int c = n >> 4, nn = n & 15;
        WB[(((ks * NC + c) * 16 + nn) * 4 + qq) * 8 + jj] = __float2bfloat16(W[f]);
    }
    __syncthreads();

    const int wave = t >> 6, lane = t & 63;
    const int r = lane & 15, q = lane >> 4;
    const int m0 = blockIdx.x * 64 + wave * 16;
    int arow = m0 + r;
    if (arow >= NN) arow = NN - 1;  // clamp: garbage rows computed, never stored

    f32x4 acc[NC];
#pragma unroll
    for (int c = 0; c < NC; ++c) acc[c] = (f32x4){0.f, 0.f, 0.f, 0.f};

#pragma unroll
    for (int ks = 0; ks < NKS; ++ks) {
        bf16_8 a;
        if constexpr (sizeof(AT) == 4) {  // f32 input, convert in-flight
            const float* xp = (const float*)X + (size_t)arow * K + ks * 32 + q * 8;
            float4 x0 = ((const float4*)xp)[0];
            float4 x1 = ((const float4*)xp)[1];
            a[0] = (__bf16)x0.x; a[1] = (__bf16)x0.y; a[2] = (__bf16)x0.z; a[3] = (__bf16)x0.w;
            a[4] = (__bf16)x1.x; a[5] = (__bf16)x1.y; a[6] = (__bf16)x1.z; a[7] = (__bf16)x1.w;
        } else {                          // bf16 input: one 16B load
            a = *(const bf16_8*)((const __hip_bfloat16*)X + (size_t)arow * K + ks * 32 + q * 8);
        }
#pragma unroll
        for (int c = 0; c < NC; ++c) {
            bf16_8 b = *(const bf16_8*)&WB[(((ks * NC + c) * 16 + r) * 4 + q) * 8];
            acc[c] = __builtin_amdgcn_mfma_f32_16x16x32_bf16(a, b, acc[c], 0, 0, 0);
        }
    }

    float dn[4];
#pragma unroll
    for (int i = 0; i < 4; ++i) {
        int gr = m0 + q * 4 + i;
        dn[i] = (gr < NN) ? dinv[gr] : 0.f;
    }
#pragma unroll
    for (int c = 0; c < NC; ++c) {
#pragma unroll
        for (int i = 0; i < 4; ++i) {
            int gr = m0 + q * 4 + i;
            if (gr < NN)
                Y[(size_t)gr * NOUT + c * 16 + r] = __float2bfloat16(dn[i] * acc[c][i]);
        }
    }
}

// ---------------------------------------------------------------------------
// Aggregation, one wave per node, bf16 gathers, f32 accumulate.
// Layer 1 (F=128): lane holds bf16x2 (feats 2l, 2l+1). relu(dinv*sum + b) -> bf16.
// ---------------------------------------------------------------------------
__global__ __launch_bounds__(256) void k_agg1(const __hip_bfloat16* __restrict__ Xw,
                                              const int* __restrict__ srcs,
                                              const unsigned* __restrict__ row_ptr,
                                              const float* __restrict__ dinv,
                                              const float* __restrict__ b1,
                                              __hip_bfloat16* __restrict__ H) {
    int wv   = (blockIdx.x * 256 + threadIdx.x) >> 6;
    int lane = threadIdx.x & 63;
    if (wv >= NN) return;
    const __hip_bfloat162* X2 = (const __hip_bfloat162*)Xw;
    float2 ac = __bfloat1622float2(X2[(size_t)wv * 64 + lane]);  // self-loop (pre-scaled)
    unsigned i  = row_ptr[wv];
    unsigned ie = row_ptr[wv + 1];
    for (; i + 1 < ie; i += 2) {
        int s0 = srcs[i], s1 = srcs[i + 1];
        float2 v0 = __bfloat1622float2(X2[(size_t)s0 * 64 + lane]);
        float2 v1 = __bfloat1622float2(X2[(size_t)s1 * 64 + lane]);
        ac.x += v0.x + v1.x;
        ac.y += v0.y + v1.y;
    }
    if (i < ie) {
        float2 v = __bfloat1622float2(X2[(size_t)srcs[i] * 64 + lane]);
        ac.x += v.x;
        ac.y += v.y;
    }
    float dn = dinv[wv];
    float o0 = fmaxf(dn * ac.x + b1[2 * lane], 0.f);
    float o1 = fmaxf(dn * ac.y + b1[2 * lane + 1], 0.f);
    ((__hip_bfloat162*)H)[(size_t)wv * 64 + lane] = __float22bfloat162_rn(make_float2(o0, o1));
}

// Layer 2 (F=64): lane holds 1 bf16. out_f32 = dinv*sum + b (no relu).
__global__ __launch_bounds__(256) void k_agg2(const __hip_bfloat16* __restrict__ Hw,
                                              const int* __restrict__ srcs,
                                              const unsigned* __restrict__ row_ptr,
                                              const float* __restrict__ dinv,
                                              const float* __restrict__ b2,
                                              float* __restrict__ out) {
    int wv   = (blockIdx.x * 256 + threadIdx.x) >> 6;
    int lane = threadIdx.x & 63;
    if (wv >= NN) return;
    float ac = __bfloat162float(Hw[(size_t)wv * 64 + lane]);  // self-loop
    unsigned i  = row_ptr[wv];
    unsigned ie = row_ptr[wv + 1];
    for (; i + 1 < ie; i += 2) {
        int s0 = srcs[i], s1 = srcs[i + 1];
        float v0 = __bfloat162float(Hw[(size_t)s0 * 64 + lane]);
        float v1 = __bfloat162float(Hw[(size_t)s1 * 64 + lane]);
        ac += v0 + v1;
    }
    if (i < ie) ac += __bfloat162float(Hw[(size_t)srcs[i] * 64 + lane]);
    out[(size_t)wv * 64 + lane] = dinv[wv] * ac + b2[lane];
}

// ---------------------------------------------------------------------------
extern "C" void kernel_launch(void* const* d_in, const int* in_sizes, int n_in,
                              void* d_out, int out_size, void* d_ws, size_t ws_size,
                              hipStream_t stream) {
    const float* x  = (const float*)d_in[0];
    const int*   ei = (const int*)d_in[1];
    const float* W1 = (const float*)d_in[2];
    const float* b1 = (const float*)d_in[3];
    const float* W2 = (const float*)d_in[4];
    const float* b2 = (const float*)d_in[5];
    float* out = (float*)d_out;

    char* w = (char*)d_ws;
    size_t off = 0;
    auto alloc = [&](size_t bytes) {
        void* p = w + off;
        off += (bytes + 255) & ~(size_t)255;
        return p;
    };
    int*      srcN    = (int*)alloc((size_t)NE * 4);
    int*      dstN    = (int*)alloc((size_t)NE * 4);
    unsigned* cnt     = (unsigned*)alloc((size_t)NN * 4);
    unsigned* row_ptr = (unsigned*)alloc((size_t)(NN + 1) * 4);
    unsigned* cursor  = (unsigned*)alloc((size_t)NN * 4);
    float*    dinv    = (float*)alloc((size_t)NN * 4);
    unsigned* bsum    = (unsigned*)alloc(256 * 4);
    unsigned* bscan   = (unsigned*)alloc(256 * 4);
    int*      srcs    = (int*)alloc((size_t)NE * 4);
    __hip_bfloat16* Xw = (__hip_bfloat16*)alloc((size_t)NN * F_H * 2);  // reused as Hw
    __hip_bfloat16* H1 = (__hip_bfloat16*)alloc((size_t)NN * F_H * 2);
    __hip_bfloat16* Hw = Xw;  // alias: Xw dead after k_agg1

    // CSR build
    k_norm_edges<<<NB_EDGE, 256, 0, stream>>>(ei, srcN, dstN);
    hipMemsetAsync(cnt, 0, (size_t)NN * 4, stream);
    k_count<<<NB_EDGE, 256, 0, stream>>>(dstN, cnt);
    k_blocksum<<<NB_NODE, 256, 0, stream>>>(cnt, bsum);
    k_scan_bsums<<<1, 256, 0, stream>>>(bsum, bscan);
    k_scan_local<<<NB_NODE, 256, 0, stream>>>(cnt, bscan, row_ptr, cursor, dinv);
    k_scatter<<<NB_EDGE, 256, 0, stream>>>(srcN, dstN, cursor, srcs);

    // Layer 1: Xw = dinv * (x @ W1); H1 = relu(dinv * agg(Xw) + b1)
    k_gemm_mfma<float, F_IN, F_H><<<(NN + 63) / 64, 256, 0, stream>>>(x, W1, dinv, Xw);
    k_agg1<<<(NN + 3) / 4, 256, 0, stream>>>(Xw, srcs, row_ptr, dinv, b1, H1);

    // Layer 2: Hw = dinv * (H1 @ W2); out = dinv * agg(Hw) + b2
    k_gemm_mfma<__hip_bfloat16, F_H, F_O><<<(NN + 63) / 64, 256, 0, stream>>>(H1, W2, dinv, Hw);
    k_agg2<<<(NN + 3) / 4, 256, 0, stream>>>(Hw, srcs, row_ptr, dinv, b2, out);
}

// Round 3
// 209.091 us; speedup vs baseline: 4.2844x; 1.5109x over previous
//
#include <hip/hip_runtime.h>
#include <hip/hip_bf16.h>

#define NN   50000
#define NE   800000
#define F_IN 128
#define F_H  128
#define F_O  64

#define BINSHIFT 7                       // 128 nodes per bin
#define NBINS    ((NN + 127) >> 7)       // 391
#define CAP      2816                    // mean 2048, sd ~45 -> +17 sigma
#define EPB      2048                    // edges per phase-A block

static constexpr int NB_NODE = (NN + 255) / 256;   // 196
static constexpr int NB_G1   = (NN + 63) / 64;     // 782 GEMM1 blocks

typedef __bf16 bf16_8 __attribute__((ext_vector_type(8)));
typedef float  f32x4  __attribute__((ext_vector_type(4)));

// ---------------------------------------------------------------------------
// MFMA GEMM body:  Y_bf16[r][c] = (SCALE ? dinv[r] : 1) * sum_k A[r][k]*W[k][c]
// Block = 64 rows (4 waves x 16 rows). W staged into LDS pre-swizzled to
// B-fragment layout [ks][c][n][q][j]; A-fragments straight from global.
// mfma_f32_16x16x32_bf16: A[m=lane&15][k=(lane>>4)*8+j],
//                         B[k][n=lane&15], D[row=(lane>>4)*4+reg][col=lane&15].
// ---------------------------------------------------------------------------
template <typename AT, int K, int NOUT, bool SCALE>
__device__ __forceinline__ void gemm_body(const AT* __restrict__ X,
                                          const float* __restrict__ W,
                                          const float* __restrict__ dinv,
                                          __hip_bfloat16* __restrict__ Y,
                                          __hip_bfloat16* WB, int blk) {
    constexpr int NKS = K / 32;
    constexpr int NC  = NOUT / 16;
    const int t = threadIdx.x;
    for (int f = t; f < K * NOUT; f += 256) {
        int k = f / NOUT, n = f % NOUT;
        int ks = k >> 5, kr = k & 31, qq = kr >> 3, jj = kr & 7;
        int c = n >> 4, nn = n & 15;
        WB[(((ks * NC + c) * 16 + nn) * 4 + qq) * 8 + jj] = __float2bfloat16(W[f]);
    }
    __syncthreads();

    const int wave = t >> 6, lane = t & 63;
    const int r = lane & 15, q = lane >> 4;
    const int m0 = blk * 64 + wave * 16;
    int arow = m0 + r;
    if (arow >= NN) arow = NN - 1;  // clamp: garbage rows computed, never stored

    f32x4 acc[NC];
#pragma unroll
    for (int c = 0; c < NC; ++c) acc[c] = (f32x4){0.f, 0.f, 0.f, 0.f};

#pragma unroll
    for (int ks = 0; ks < NKS; ++ks) {
        bf16_8 a;
        if constexpr (sizeof(AT) == 4) {
            const float* xp = (const float*)X + (size_t)arow * K + ks * 32 + q * 8;
            float4 x0 = ((const float4*)xp)[0];
            float4 x1 = ((const float4*)xp)[1];
            a[0] = (__bf16)x0.x; a[1] = (__bf16)x0.y; a[2] = (__bf16)x0.z; a[3] = (__bf16)x0.w;
            a[4] = (__bf16)x1.x; a[5] = (__bf16)x1.y; a[6] = (__bf16)x1.z; a[7] = (__bf16)x1.w;
        } else {
            a = *(const bf16_8*)((const __hip_bfloat16*)X + (size_t)arow * K + ks * 32 + q * 8);
        }
#pragma unroll
        for (int c = 0; c < NC; ++c) {
            bf16_8 b = *(const bf16_8*)&WB[(((ks * NC + c) * 16 + r) * 4 + q) * 8];
            acc[c] = __builtin_amdgcn_mfma_f32_16x16x32_bf16(a, b, acc[c], 0, 0, 0);
        }
    }

#pragma unroll
    for (int c = 0; c < NC; ++c) {
#pragma unroll
        for (int i = 0; i < 4; ++i) {
            int gr = m0 + q * 4 + i;
            if (gr < NN) {
                float v = acc[c][i];
                if constexpr (SCALE) v *= dinv[gr];
                Y[(size_t)gr * NOUT + c * 16 + r] = __float2bfloat16(v);
            }
        }
    }
}

// ---------------------------------------------------------------------------
// Fused: blocks [0,NB_G1) do GEMM1 (x@W1 -> Xw, UNscaled);
//        blocks [NB_G1, NB_G1+NBINS) bin edges by dst>>7 into binbuf.
// Roles are fully independent (GEMM1 needs no graph data; binning needs no x).
// ---------------------------------------------------------------------------
__global__ __launch_bounds__(256) void k_fuseA(const float* __restrict__ X,
                                               const float* __restrict__ W1,
                                               __hip_bfloat16* __restrict__ Xw,
                                               const int* __restrict__ ei32,
                                               int2* __restrict__ binbuf,
                                               unsigned* __restrict__ bincnt) {
    __shared__ __align__(16) char smem[32768];  // GEMM WB (32KB) / binning hists (4.7KB)
    const int t = threadIdx.x;

    if (blockIdx.x < NB_G1) {
        gemm_body<float, F_IN, F_H, false>(X, W1, nullptr, Xw,
                                           (__hip_bfloat16*)smem, blockIdx.x);
        return;
    }

    // ---- binning role ----
    unsigned* hist = (unsigned*)smem;        // [NBINS]
    unsigned* base = hist + NBINS;           // [NBINS]
    unsigned* rank = base + NBINS;           // [NBINS]
    for (int i = t; i < NBINS; i += 256) { hist[i] = 0u; rank[i] = 0u; }
    __syncthreads();

    const bool is64 = ((ei32[1] | ei32[3] | ei32[5] | ei32[7]) == 0);
    const int e0 = (blockIdx.x - NB_G1) * EPB;
    int es[8], ed[8];
#pragma unroll
    for (int j = 0; j < 8; ++j) {
        int e = e0 + t + j * 256;
        if (e < NE) {
            if (is64) {
                const long long* p = (const long long*)ei32;
                es[j] = (int)p[e];
                ed[j] = (int)p[NE + e];
            } else {
                es[j] = ei32[e];
                ed[j] = ei32[NE + e];
            }
        } else ed[j] = -1;
    }
#pragma unroll
    for (int j = 0; j < 8; ++j)
        if (ed[j] >= 0) atomicAdd(&hist[ed[j] >> BINSHIFT], 1u);
    __syncthreads();
    for (int b = t; b < NBINS; b += 256)
        base[b] = atomicAdd(&bincnt[b], hist[b]);  // reserve contiguous chunk
    __syncthreads();
#pragma unroll
    for (int j = 0; j < 8; ++j) {
        if (ed[j] >= 0) {
            int b = ed[j] >> BINSHIFT;
            unsigned rk = atomicAdd(&rank[b], 1u);
            binbuf[(size_t)b * CAP + base[b] + rk] = make_int2(es[j], ed[j]);
        }
    }
}

// ---------------------------------------------------------------------------
// Per-node in-degree from bin buffers — LDS atomics only (128 nodes/bin).
// ---------------------------------------------------------------------------
__global__ __launch_bounds__(256) void k_bincount(const int2* __restrict__ binbuf,
                                                  const unsigned* __restrict__ bincnt,
                                                  unsigned* __restrict__ cnt) {
    __shared__ unsigned h[128];
    const int b = blockIdx.x;
    if (threadIdx.x < 128) h[threadIdx.x] = 0u;
    __syncthreads();
    const unsigned n = bincnt[b];
    for (unsigned i = threadIdx.x; i < n; i += 256)
        atomicAdd(&h[binbuf[(size_t)b * CAP + i].y & 127], 1u);
    __syncthreads();
    int node = (b << BINSHIFT) + threadIdx.x;
    if (threadIdx.x < 128 && node < NN) cnt[node] = h[threadIdx.x];
}

// ---------------------------------------------------------------------------
// Exclusive scan over cnt -> row_ptr, dinv (3 kernels).
// ---------------------------------------------------------------------------
__global__ __launch_bounds__(256) void k_blocksum(const unsigned* __restrict__ cnt,
                                                  unsigned* __restrict__ bsum) {
    __shared__ unsigned s[256];
    int i = blockIdx.x * 256 + threadIdx.x;
    unsigned v = (i < NN) ? cnt[i] : 0u;
    s[threadIdx.x] = v;
    __syncthreads();
    for (int off = 128; off > 0; off >>= 1) {
        if (threadIdx.x < off) s[threadIdx.x] += s[threadIdx.x + off];
        __syncthreads();
    }
    if (threadIdx.x == 0) bsum[blockIdx.x] = s[0];
}

__global__ __launch_bounds__(256) void k_scan_bsums(const unsigned* __restrict__ bsum,
                                                    unsigned* __restrict__ bscan) {
    __shared__ unsigned s[256];
    unsigned v = (threadIdx.x < NB_NODE) ? bsum[threadIdx.x] : 0u;
    s[threadIdx.x] = v;
    __syncthreads();
    for (int off = 1; off < 256; off <<= 1) {
        unsigned t = (threadIdx.x >= (unsigned)off) ? s[threadIdx.x - off] : 0u;
        __syncthreads();
        s[threadIdx.x] += t;
        __syncthreads();
    }
    if (threadIdx.x < NB_NODE) bscan[threadIdx.x] = s[threadIdx.x] - v;  // exclusive
}

__global__ __launch_bounds__(256) void k_scan_local(const unsigned* __restrict__ cnt,
                                                    const unsigned* __restrict__ bscan,
                                                    unsigned* __restrict__ row_ptr,
                                                    float* __restrict__ dinv) {
    __shared__ unsigned s[256];
    int i = blockIdx.x * 256 + threadIdx.x;
    unsigned v = (i < NN) ? cnt[i] : 0u;
    s[threadIdx.x] = v;
    __syncthreads();
    for (int off = 1; off < 256; off <<= 1) {
        unsigned t = (threadIdx.x >= (unsigned)off) ? s[threadIdx.x - off] : 0u;
        __syncthreads();
        s[threadIdx.x] += t;
        __syncthreads();
    }
    if (i < NN) {
        row_ptr[i] = bscan[blockIdx.x] + s[threadIdx.x] - v;  // exclusive prefix
        dinv[i]    = 1.0f / sqrtf((float)(v + 1u));           // +1 self-loop
    }
    if (i == 0) row_ptr[NN] = NE;
}

// ---------------------------------------------------------------------------
// Phase B: bin -> CSR. One block per bin; cursors in LDS (all atomics LDS);
// writes confined to the bin's ~8KB srcs region (L2-local, full lines).
// ---------------------------------------------------------------------------
__global__ __launch_bounds__(256) void k_phaseB(const int2* __restrict__ binbuf,
                                                const unsigned* __restrict__ bincnt,
                                                const unsigned* __restrict__ row_ptr,
                                                int* __restrict__ srcs) {
    __shared__ unsigned lcur[128];
    const int b = blockIdx.x;
    const int node0 = b << BINSHIFT;
    if (threadIdx.x < 128) {
        int node = node0 + threadIdx.x;
        lcur[threadIdx.x] = (node < NN) ? row_ptr[node] : 0u;
    }
    __syncthreads();
    const unsigned n = bincnt[b];
    for (unsigned i = threadIdx.x; i < n; i += 256) {
        int2 p = binbuf[(size_t)b * CAP + i];
        unsigned pos = atomicAdd(&lcur[p.y & 127], 1u);
        srcs[pos] = p.x;
    }
}

// ---------------------------------------------------------------------------
// Aggregation, one wave per node, bf16 gathers, f32 accumulate.
// Layer 1: Xw UNscaled -> weight each gathered row by dinv[src].
// H = relu(dinv[v]*(sum_e dinv[s]*Xw[s] + dinv[v]*Xw[v]) + b1)
// ---------------------------------------------------------------------------
__global__ __launch_bounds__(256) void k_agg1(const __hip_bfloat16* __restrict__ Xw,
                                              const int* __restrict__ srcs,
                                              const unsigned* __restrict__ row_ptr,
                                              const float* __restrict__ dinv,
                                              const float* __restrict__ b1,
                                              __hip_bfloat16* __restrict__ H) {
    int wv   = (blockIdx.x * 256 + threadIdx.x) >> 6;
    int lane = threadIdx.x & 63;
    if (wv >= NN) return;
    const __hip_bfloat162* X2 = (const __hip_bfloat162*)Xw;
    const float dn = dinv[wv];
    float2 self = __bfloat1622float2(X2[(size_t)wv * 64 + lane]);
    float2 ac0 = make_float2(dn * self.x, dn * self.y);
    float2 ac1 = make_float2(0.f, 0.f);
    unsigned i  = row_ptr[wv];
    unsigned ie = row_ptr[wv + 1];
    for (; i + 3 < ie; i += 4) {
        int s0 = srcs[i], s1 = srcs[i + 1], s2 = srcs[i + 2], s3 = srcs[i + 3];
        float d0 = dinv[s0], d1 = dinv[s1], d2 = dinv[s2], d3 = dinv[s3];
        float2 v0 = __bfloat1622float2(X2[(size_t)s0 * 64 + lane]);
        float2 v1 = __bfloat1622float2(X2[(size_t)s1 * 64 + lane]);
        float2 v2 = __bfloat1622float2(X2[(size_t)s2 * 64 + lane]);
        float2 v3 = __bfloat1622float2(X2[(size_t)s3 * 64 + lane]);
        ac0.x += d0 * v0.x; ac0.y += d0 * v0.y;
        ac1.x += d1 * v1.x; ac1.y += d1 * v1.y;
        ac0.x += d2 * v2.x; ac0.y += d2 * v2.y;
        ac1.x += d3 * v3.x; ac1.y += d3 * v3.y;
    }
    for (; i < ie; ++i) {
        int s = srcs[i];
        float d = dinv[s];
        float2 v = __bfloat1622float2(X2[(size_t)s * 64 + lane]);
        ac0.x += d * v.x; ac0.y += d * v.y;
    }
    float o0 = fmaxf(dn * (ac0.x + ac1.x) + b1[2 * lane], 0.f);
    float o1 = fmaxf(dn * (ac0.y + ac1.y) + b1[2 * lane + 1], 0.f);
    ((__hip_bfloat162*)H)[(size_t)wv * 64 + lane] = __float22bfloat162_rn(make_float2(o0, o1));
}

// Layer 2 GEMM (Hw = dinv * (H1 @ W2)), standalone.
__global__ __launch_bounds__(256) void k_gemm2(const __hip_bfloat16* __restrict__ H1,
                                               const float* __restrict__ W2,
                                               const float* __restrict__ dinv,
                                               __hip_bfloat16* __restrict__ Hw) {
    __shared__ __align__(16) __hip_bfloat16 WB[(F_H / 32) * (F_O / 16) * 512];
    gemm_body<__hip_bfloat16, F_H, F_O, true>(H1, W2, dinv, Hw, WB, blockIdx.x);
}

// Layer 2 agg (Hw pre-scaled): out = dinv[v]*(sum_e Hw[s] + Hw[v]) + b2
__global__ __launch_bounds__(256) void k_agg2(const __hip_bfloat16* __restrict__ Hw,
                                              const int* __restrict__ srcs,
                                              const unsigned* __restrict__ row_ptr,
                                              const float* __restrict__ dinv,
                                              const float* __restrict__ b2,
                                              float* __restrict__ out) {
    int wv   = (blockIdx.x * 256 + threadIdx.x) >> 6;
    int lane = threadIdx.x & 63;
    if (wv >= NN) return;
    float ac0 = __bfloat162float(Hw[(size_t)wv * 64 + lane]);  // self-loop
    float ac1 = 0.f;
    unsigned i  = row_ptr[wv];
    unsigned ie = row_ptr[wv + 1];
    for (; i + 3 < ie; i += 4) {
        int s0 = srcs[i], s1 = srcs[i + 1], s2 = srcs[i + 2], s3 = srcs[i + 3];
        float v0 = __bfloat162float(Hw[(size_t)s0 * 64 + lane]);
        float v1 = __bfloat162float(Hw[(size_t)s1 * 64 + lane]);
        float v2 = __bfloat162float(Hw[(size_t)s2 * 64 + lane]);
        float v3 = __bfloat162float(Hw[(size_t)s3 * 64 + lane]);
        ac0 += v0 + v2;
        ac1 += v1 + v3;
    }
    for (; i < ie; ++i) ac0 += __bfloat162float(Hw[(size_t)srcs[i] * 64 + lane]);
    out[(size_t)wv * 64 + lane] = dinv[wv] * (ac0 + ac1) + b2[lane];
}

// ---------------------------------------------------------------------------
extern "C" void kernel_launch(void* const* d_in, const int* in_sizes, int n_in,
                              void* d_out, int out_size, void* d_ws, size_t ws_size,
                              hipStream_t stream) {
    const float* x  = (const float*)d_in[0];
    const int*   ei = (const int*)d_in[1];
    const float* W1 = (const float*)d_in[2];
    const float* b1 = (const float*)d_in[3];
    const float* W2 = (const float*)d_in[4];
    const float* b2 = (const float*)d_in[5];
    float* out = (float*)d_out;

    char* w = (char*)d_ws;
    size_t off = 0;
    auto alloc = [&](size_t bytes) {
        void* p = w + off;
        off += (bytes + 255) & ~(size_t)255;
        return p;
    };
    unsigned* cnt     = (unsigned*)alloc((size_t)NN * 4);
    unsigned* row_ptr = (unsigned*)alloc((size_t)(NN + 1) * 4);
    float*    dinv    = (float*)alloc((size_t)NN * 4);
    unsigned* bsum    = (unsigned*)alloc(256 * 4);
    unsigned* bscan   = (unsigned*)alloc(256 * 4);
    unsigned* bincnt  = (unsigned*)alloc((size_t)NBINS * 4);
    int*      srcs    = (int*)alloc((size_t)NE * 4);
    int2*     binbuf  = (int2*)alloc((size_t)NBINS * CAP * 8);
    __hip_bfloat16* Xw = (__hip_bfloat16*)alloc((size_t)NN * F_H * 2);  // reused as Hw
    __hip_bfloat16* H1 = (__hip_bfloat16*)alloc((size_t)NN * F_H * 2);
    __hip_bfloat16* Hw = Xw;  // alias: Xw dead after k_agg1

    const int NB_BIN = (NE + EPB - 1) / EPB;  // 391 == NBINS by construction

    hipMemsetAsync(bincnt, 0, (size_t)NBINS * 4, stream);
    // GEMM1 (independent) fused with edge binning
    k_fuseA<<<NB_G1 + NB_BIN, 256, 0, stream>>>(x, W1, Xw, ei, binbuf, bincnt);
    k_bincount<<<NBINS, 256, 0, stream>>>(binbuf, bincnt, cnt);
    k_blocksum<<<NB_NODE, 256, 0, stream>>>(cnt, bsum);
    k_scan_bsums<<<1, 256, 0, stream>>>(bsum, bscan);
    k_scan_local<<<NB_NODE, 256, 0, stream>>>(cnt, bscan, row_ptr, dinv);
    k_phaseB<<<NBINS, 256, 0, stream>>>(binbuf, bincnt, row_ptr, srcs);

    k_agg1<<<(NN + 3) / 4, 256, 0, stream>>>(Xw, srcs, row_ptr, dinv, b1, H1);
    k_gemm2<<<(NN + 63) / 64, 256, 0, stream>>>(H1, W2, dinv, Hw);
    k_agg2<<<(NN + 3) / 4, 256, 0, stream>>>(Hw, srcs, row_ptr, dinv, b2, out);
}

// Round 4
// 192.460 us; speedup vs baseline: 4.6546x; 1.0864x over previous
//
#include <hip/hip_runtime.h>
#include <hip/hip_bf16.h>

#define NN   50000
#define NE   800000
#define F_IN 128
#define F_H  128
#define F_O  64

#define BINSHIFT 7                       // 128 nodes per bin
#define NBINS    ((NN + 127) >> 7)       // 391
#define CAP      2816                    // mean 2048, sd ~45 -> +17 sigma
#define EPB      2048                    // edges per phase-A binning block

static constexpr int NB_G1 = (NN + 63) / 64;     // 782 GEMM1 blocks

typedef __bf16 bf16_8 __attribute__((ext_vector_type(8)));
typedef float  f32x4  __attribute__((ext_vector_type(4)));

// ---------------------------------------------------------------------------
// MFMA GEMM body:  Y_bf16[r][c] = (SCALE ? dinv[r] : 1) * sum_k A[r][k]*W[k][c]
// Block = 64 rows (4 waves x 16 rows). W staged into LDS pre-swizzled to
// B-fragment layout [ks][c][n][q][j]; A-fragments straight from global.
// mfma_f32_16x16x32_bf16: A[m=lane&15][k=(lane>>4)*8+j],
//                         B[k][n=lane&15], D[row=(lane>>4)*4+reg][col=lane&15].
// ---------------------------------------------------------------------------
template <typename AT, int K, int NOUT, bool SCALE>
__device__ __forceinline__ void gemm_body(const AT* __restrict__ X,
                                          const float* __restrict__ W,
                                          const float* __restrict__ dinv,
                                          __hip_bfloat16* __restrict__ Y,
                                          __hip_bfloat16* WB, int blk) {
    constexpr int NKS = K / 32;
    constexpr int NC  = NOUT / 16;
    const int t = threadIdx.x;
    for (int f = t; f < K * NOUT; f += 256) {
        int k = f / NOUT, n = f % NOUT;
        int ks = k >> 5, kr = k & 31, qq = kr >> 3, jj = kr & 7;
        int c = n >> 4, nn = n & 15;
        WB[(((ks * NC + c) * 16 + nn) * 4 + qq) * 8 + jj] = __float2bfloat16(W[f]);
    }
    __syncthreads();

    const int wave = t >> 6, lane = t & 63;
    const int r = lane & 15, q = lane >> 4;
    const int m0 = blk * 64 + wave * 16;
    int arow = m0 + r;
    if (arow >= NN) arow = NN - 1;  // clamp: garbage rows computed, never stored

    f32x4 acc[NC];
#pragma unroll
    for (int c = 0; c < NC; ++c) acc[c] = (f32x4){0.f, 0.f, 0.f, 0.f};

#pragma unroll
    for (int ks = 0; ks < NKS; ++ks) {
        bf16_8 a;
        if constexpr (sizeof(AT) == 4) {
            const float* xp = (const float*)X + (size_t)arow * K + ks * 32 + q * 8;
            float4 x0 = ((const float4*)xp)[0];
            float4 x1 = ((const float4*)xp)[1];
            a[0] = (__bf16)x0.x; a[1] = (__bf16)x0.y; a[2] = (__bf16)x0.z; a[3] = (__bf16)x0.w;
            a[4] = (__bf16)x1.x; a[5] = (__bf16)x1.y; a[6] = (__bf16)x1.z; a[7] = (__bf16)x1.w;
        } else {
            a = *(const bf16_8*)((const __hip_bfloat16*)X + (size_t)arow * K + ks * 32 + q * 8);
        }
#pragma unroll
        for (int c = 0; c < NC; ++c) {
            bf16_8 b = *(const bf16_8*)&WB[(((ks * NC + c) * 16 + r) * 4 + q) * 8];
            acc[c] = __builtin_amdgcn_mfma_f32_16x16x32_bf16(a, b, acc[c], 0, 0, 0);
        }
    }

#pragma unroll
    for (int c = 0; c < NC; ++c) {
#pragma unroll
        for (int i = 0; i < 4; ++i) {
            int gr = m0 + q * 4 + i;
            if (gr < NN) {
                float v = acc[c][i];
                if constexpr (SCALE) v *= dinv[gr];
                Y[(size_t)gr * NOUT + c * 16 + r] = __float2bfloat16(v);
            }
        }
    }
}

// ---------------------------------------------------------------------------
// Fused: blocks [0,NB_G1) do GEMM1 (x@W1 -> Xw, UNscaled);
//        blocks [NB_G1, NB_G1+NBINS) bin edges by dst>>7 into packed binbuf.
// Packed entry: (src << 7) | (dst & 127)  — src < 2^17 fits.
// bincnt[b] ends as the bin's total edge count (reused by the scan).
// ---------------------------------------------------------------------------
__global__ __launch_bounds__(256) void k_fuseA(const float* __restrict__ X,
                                               const float* __restrict__ W1,
                                               __hip_bfloat16* __restrict__ Xw,
                                               const int* __restrict__ ei32,
                                               int* __restrict__ binbuf,
                                               unsigned* __restrict__ bincnt) {
    __shared__ __align__(16) char smem[32768];  // GEMM WB (32KB) / binning hists (4.7KB)
    const int t = threadIdx.x;

    if (blockIdx.x < NB_G1) {
        gemm_body<float, F_IN, F_H, false>(X, W1, nullptr, Xw,
                                           (__hip_bfloat16*)smem, blockIdx.x);
        return;
    }

    // ---- binning role ----
    unsigned* hist = (unsigned*)smem;        // [NBINS]
    unsigned* base = hist + NBINS;           // [NBINS]
    unsigned* rank = base + NBINS;           // [NBINS]
    for (int i = t; i < NBINS; i += 256) { hist[i] = 0u; rank[i] = 0u; }
    __syncthreads();

    const bool is64 = ((ei32[1] | ei32[3] | ei32[5] | ei32[7]) == 0);
    const int e0 = (blockIdx.x - NB_G1) * EPB;
    int pk[8], bin[8];
#pragma unroll
    for (int j = 0; j < 8; ++j) {
        int e = e0 + t + j * 256;
        if (e < NE) {
            int s, d;
            if (is64) {
                const long long* p = (const long long*)ei32;
                s = (int)p[e];
                d = (int)p[NE + e];
            } else {
                s = ei32[e];
                d = ei32[NE + e];
            }
            pk[j]  = (s << BINSHIFT) | (d & 127);
            bin[j] = d >> BINSHIFT;
        } else bin[j] = -1;
    }
#pragma unroll
    for (int j = 0; j < 8; ++j)
        if (bin[j] >= 0) atomicAdd(&hist[bin[j]], 1u);
    __syncthreads();
    for (int b = t; b < NBINS; b += 256)
        base[b] = atomicAdd(&bincnt[b], hist[b]);  // reserve contiguous chunk
    __syncthreads();
#pragma unroll
    for (int j = 0; j < 8; ++j) {
        if (bin[j] >= 0) {
            unsigned rk = atomicAdd(&rank[bin[j]], 1u);
            binbuf[(size_t)bin[j] * CAP + base[bin[j]] + rk] = pk[j];
        }
    }
}

// ---------------------------------------------------------------------------
// Exclusive scan of bin totals (391 bins, one block).
// ---------------------------------------------------------------------------
__global__ __launch_bounds__(512) void k_binscan(const unsigned* __restrict__ bincnt,
                                                 unsigned* __restrict__ bscan) {
    __shared__ unsigned s[512];
    const int t = threadIdx.x;
    unsigned v = (t < NBINS) ? bincnt[t] : 0u;
    s[t] = v;
    __syncthreads();
    for (int off = 1; off < 512; off <<= 1) {
        unsigned u = (t >= off) ? s[t - off] : 0u;
        __syncthreads();
        s[t] += u;
        __syncthreads();
    }
    if (t < NBINS) bscan[t] = s[t] - v;  // exclusive
}

// ---------------------------------------------------------------------------
// Phase B (one block per bin): local 128-node histogram from the bin buffer,
// LDS scan -> row_ptr + dinv + LDS cursors, then scatter src ids into CSR.
// All atomics are LDS; srcs writes confined to the bin's ~8KB region.
// ---------------------------------------------------------------------------
__global__ __launch_bounds__(256) void k_phaseB(const int* __restrict__ binbuf,
                                                const unsigned* __restrict__ bincnt,
                                                const unsigned* __restrict__ bscan,
                                                unsigned* __restrict__ row_ptr,
                                                float* __restrict__ dinv,
                                                int* __restrict__ srcs) {
    __shared__ unsigned h[128];
    __shared__ unsigned cur[128];
    const int b = blockIdx.x, t = threadIdx.x;
    if (t < 128) h[t] = 0u;
    __syncthreads();
    const unsigned n = bincnt[b];
    const int* buf = binbuf + (size_t)b * CAP;
    for (unsigned i = t; i < n; i += 256)
        atomicAdd(&h[buf[i] & 127], 1u);
    __syncthreads();
    if (t < 128) cur[t] = h[t];
    __syncthreads();
    for (int off = 1; off < 128; off <<= 1) {
        unsigned u = (t < 128 && t >= off) ? cur[t - off] : 0u;
        __syncthreads();
        if (t < 128) cur[t] += u;
        __syncthreads();
    }
    if (t < 128) {
        unsigned ex = bscan[b] + cur[t] - h[t];  // exclusive prefix
        int node = (b << BINSHIFT) + t;
        if (node < NN) {
            row_ptr[node] = ex;
            dinv[node]    = rsqrtf((float)(h[t] + 1u));  // +1 self-loop
        }
        cur[t] = ex;  // cursor
    }
    if (b == NBINS - 1 && t == 0) row_ptr[NN] = NE;
    __syncthreads();
    for (unsigned i = t; i < n; i += 256) {
        int p = buf[i];
        unsigned pos = atomicAdd(&cur[p & 127], 1u);
        srcs[pos] = p >> BINSHIFT;
    }
}

// ---------------------------------------------------------------------------
// Layer-1 aggregation: one wave per node, 16 lanes x 16B per gathered row
// (4 edges per row-load instruction), f32 accumulate, cross-quad reduction.
// H = relu(dinv[v]*(sum_e dinv[s]*Xw[s] + dinv[v]*Xw[v]) + b1)
// ---------------------------------------------------------------------------
__global__ __launch_bounds__(256) void k_agg1(const __hip_bfloat16* __restrict__ Xw,
                                              const int* __restrict__ srcs,
                                              const unsigned* __restrict__ row_ptr,
                                              const float* __restrict__ dinv,
                                              const float* __restrict__ b1,
                                              __hip_bfloat16* __restrict__ H) {
    const int wv   = (blockIdx.x * 256 + threadIdx.x) >> 6;
    const int lane = threadIdx.x & 63;
    if (wv >= NN) return;
    const int sub = lane >> 4;      // 0..3: which edge of the group of 4
    const int fl  = lane & 15;      // feature slice: 8*fl .. 8*fl+7
    const float dn = dinv[wv];

    float acc[8];
    bf16_8 self = *(const bf16_8*)(Xw + (size_t)wv * F_H + fl * 8);
    const float sw = (sub == 0) ? dn : 0.f;
#pragma unroll
    for (int j = 0; j < 8; ++j) acc[j] = sw * (float)self[j];

    const unsigned ie = row_ptr[wv + 1];
    for (unsigned i = row_ptr[wv] + sub; i < ie; i += 4) {
        int s = srcs[i];
        float dsc = dinv[s];
        bf16_8 row = *(const bf16_8*)(Xw + (size_t)s * F_H + fl * 8);
#pragma unroll
        for (int j = 0; j < 8; ++j) acc[j] += dsc * (float)row[j];
    }
#pragma unroll
    for (int j = 0; j < 8; ++j) {
        acc[j] += __shfl_xor(acc[j], 16, 64);
        acc[j] += __shfl_xor(acc[j], 32, 64);
    }
    if (sub == 0) {
        bf16_8 o;
#pragma unroll
        for (int j = 0; j < 8; ++j) {
            float v = fmaxf(dn * acc[j] + b1[fl * 8 + j], 0.f);
            o[j] = (__bf16)v;
        }
        *(bf16_8*)(H + (size_t)wv * F_H + fl * 8) = o;
    }
}

// Layer 2 GEMM (Hw = dinv * (H1 @ W2)), standalone.
__global__ __launch_bounds__(256) void k_gemm2(const __hip_bfloat16* __restrict__ H1,
                                               const float* __restrict__ W2,
                                               const float* __restrict__ dinv,
                                               __hip_bfloat16* __restrict__ Hw) {
    __shared__ __align__(16) __hip_bfloat16 WB[(F_H / 32) * (F_O / 16) * 512];
    gemm_body<__hip_bfloat16, F_H, F_O, true>(H1, W2, dinv, Hw, WB, blockIdx.x);
}

// ---------------------------------------------------------------------------
// Layer-2 aggregation: one wave per node, 8 lanes x 16B per row
// (8 edges per row-load instruction). Hw is pre-scaled by dinv[src].
// out = dinv[v]*(sum_e Hw[s] + Hw[v]) + b2   (f32 output)
// ---------------------------------------------------------------------------
__global__ __launch_bounds__(256) void k_agg2(const __hip_bfloat16* __restrict__ Hw,
                                              const int* __restrict__ srcs,
                                              const unsigned* __restrict__ row_ptr,
                                              const float* __restrict__ dinv,
                                              const float* __restrict__ b2,
                                              float* __restrict__ out) {
    const int wv   = (blockIdx.x * 256 + threadIdx.x) >> 6;
    const int lane = threadIdx.x & 63;
    if (wv >= NN) return;
    const int sub = lane >> 3;      // 0..7
    const int fl  = lane & 7;       // feature slice: 8*fl .. 8*fl+7

    float acc[8];
    bf16_8 self = *(const bf16_8*)(Hw + (size_t)wv * F_O + fl * 8);
#pragma unroll
    for (int j = 0; j < 8; ++j) acc[j] = (sub == 0) ? (float)self[j] : 0.f;

    const unsigned ie = row_ptr[wv + 1];
    for (unsigned i = row_ptr[wv] + sub; i < ie; i += 8) {
        int s = srcs[i];
        bf16_8 row = *(const bf16_8*)(Hw + (size_t)s * F_O + fl * 8);
#pragma unroll
        for (int j = 0; j < 8; ++j) acc[j] += (float)row[j];
    }
#pragma unroll
    for (int j = 0; j < 8; ++j) {
        acc[j] += __shfl_xor(acc[j], 8, 64);
        acc[j] += __shfl_xor(acc[j], 16, 64);
        acc[j] += __shfl_xor(acc[j], 32, 64);
    }
    if (sub == 0) {
        float dn = dinv[wv];
        float4 o0 = make_float4(dn * acc[0] + b2[fl * 8 + 0], dn * acc[1] + b2[fl * 8 + 1],
                                dn * acc[2] + b2[fl * 8 + 2], dn * acc[3] + b2[fl * 8 + 3]);
        float4 o1 = make_float4(dn * acc[4] + b2[fl * 8 + 4], dn * acc[5] + b2[fl * 8 + 5],
                                dn * acc[6] + b2[fl * 8 + 6], dn * acc[7] + b2[fl * 8 + 7]);
        float4* op = (float4*)(out + (size_t)wv * F_O + fl * 8);
        op[0] = o0;
        op[1] = o1;
    }
}

// ---------------------------------------------------------------------------
extern "C" void kernel_launch(void* const* d_in, const int* in_sizes, int n_in,
                              void* d_out, int out_size, void* d_ws, size_t ws_size,
                              hipStream_t stream) {
    const float* x  = (const float*)d_in[0];
    const int*   ei = (const int*)d_in[1];
    const float* W1 = (const float*)d_in[2];
    const float* b1 = (const float*)d_in[3];
    const float* W2 = (const float*)d_in[4];
    const float* b2 = (const float*)d_in[5];
    float* out = (float*)d_out;

    char* w = (char*)d_ws;
    size_t off = 0;
    auto alloc = [&](size_t bytes) {
        void* p = w + off;
        off += (bytes + 255) & ~(size_t)255;
        return p;
    };
    unsigned* row_ptr = (unsigned*)alloc((size_t)(NN + 1) * 4);
    float*    dinv    = (float*)alloc((size_t)NN * 4);
    unsigned* bincnt  = (unsigned*)alloc((size_t)NBINS * 4);
    unsigned* bscan   = (unsigned*)alloc((size_t)NBINS * 4);
    int*      srcs    = (int*)alloc((size_t)NE * 4);
    int*      binbuf  = (int*)alloc((size_t)NBINS * CAP * 4);
    __hip_bfloat16* Xw = (__hip_bfloat16*)alloc((size_t)NN * F_H * 2);  // reused as Hw
    __hip_bfloat16* H1 = (__hip_bfloat16*)alloc((size_t)NN * F_H * 2);
    __hip_bfloat16* Hw = Xw;  // alias: Xw dead after k_agg1

    const int NB_BIN = (NE + EPB - 1) / EPB;  // 391

    hipMemsetAsync(bincnt, 0, (size_t)NBINS * 4, stream);
    k_fuseA<<<NB_G1 + NB_BIN, 256, 0, stream>>>(x, W1, Xw, ei, binbuf, bincnt);
    k_binscan<<<1, 512, 0, stream>>>(bincnt, bscan);
    k_phaseB<<<NBINS, 256, 0, stream>>>(binbuf, bincnt, bscan, row_ptr, dinv, srcs);

    k_agg1<<<(NN + 3) / 4, 256, 0, stream>>>(Xw, srcs, row_ptr, dinv, b1, H1);
    k_gemm2<<<(NN + 63) / 64, 256, 0, stream>>>(H1, W2, dinv, Hw);
    k_agg2<<<(NN + 3) / 4, 256, 0, stream>>>(Hw, srcs, row_ptr, dinv, b2, out);
}

// Round 5
// 192.090 us; speedup vs baseline: 4.6636x; 1.0019x over previous
//
#include <hip/hip_runtime.h>
#include <hip/hip_bf16.h>

#define NN   50000
#define NE   800000
#define F_IN 128
#define F_H  128
#define F_O  64

#define BINSHIFT 7                       // 128 nodes per bin
#define NBINS    ((NN + 127) >> 7)       // 391
#define CAP      2816                    // mean 2048, sd ~45 -> +17 sigma
#define EPB      2048                    // edges per binning block

static constexpr int NB_G1  = (NN + 63) / 64;          // 782 GEMM1 blocks
static constexpr int NB_BIN = (NE + EPB - 1) / EPB;    // 391 binning blocks

typedef __bf16 bf16_8 __attribute__((ext_vector_type(8)));
typedef float  f32x4  __attribute__((ext_vector_type(4)));

// ---------------------------------------------------------------------------
// MFMA GEMM body:  Y_bf16[r][c] = (SCALE ? dinv[r] : 1) * sum_k A[r][k]*W[k][c]
// Block = 64 rows (4 waves x 16 rows). W staged into LDS pre-swizzled to
// B-fragment layout [ks][c][n][q][j]; A-fragments straight from global.
// mfma_f32_16x16x32_bf16: A[m=lane&15][k=(lane>>4)*8+j],
//                         B[k][n=lane&15], D[row=(lane>>4)*4+reg][col=lane&15].
// ---------------------------------------------------------------------------
template <typename AT, int K, int NOUT, bool SCALE>
__device__ __forceinline__ void gemm_body(const AT* __restrict__ X,
                                          const float* __restrict__ W,
                                          const float* __restrict__ dinv,
                                          __hip_bfloat16* __restrict__ Y,
                                          __hip_bfloat16* WB, int blk) {
    constexpr int NKS = K / 32;
    constexpr int NC  = NOUT / 16;
    const int t = threadIdx.x;
    for (int f = t; f < K * NOUT; f += 256) {
        int k = f / NOUT, n = f % NOUT;
        int ks = k >> 5, kr = k & 31, qq = kr >> 3, jj = kr & 7;
        int c = n >> 4, nn = n & 15;
        WB[(((ks * NC + c) * 16 + nn) * 4 + qq) * 8 + jj] = __float2bfloat16(W[f]);
    }
    __syncthreads();

    const int wave = t >> 6, lane = t & 63;
    const int r = lane & 15, q = lane >> 4;
    const int m0 = blk * 64 + wave * 16;
    int arow = m0 + r;
    if (arow >= NN) arow = NN - 1;  // clamp: garbage rows computed, never stored

    f32x4 acc[NC];
#pragma unroll
    for (int c = 0; c < NC; ++c) acc[c] = (f32x4){0.f, 0.f, 0.f, 0.f};

#pragma unroll
    for (int ks = 0; ks < NKS; ++ks) {
        bf16_8 a;
        if constexpr (sizeof(AT) == 4) {
            const float* xp = (const float*)X + (size_t)arow * K + ks * 32 + q * 8;
            float4 x0 = ((const float4*)xp)[0];
            float4 x1 = ((const float4*)xp)[1];
            a[0] = (__bf16)x0.x; a[1] = (__bf16)x0.y; a[2] = (__bf16)x0.z; a[3] = (__bf16)x0.w;
            a[4] = (__bf16)x1.x; a[5] = (__bf16)x1.y; a[6] = (__bf16)x1.z; a[7] = (__bf16)x1.w;
        } else {
            a = *(const bf16_8*)((const __hip_bfloat16*)X + (size_t)arow * K + ks * 32 + q * 8);
        }
#pragma unroll
        for (int c = 0; c < NC; ++c) {
            bf16_8 b = *(const bf16_8*)&WB[(((ks * NC + c) * 16 + r) * 4 + q) * 8];
            acc[c] = __builtin_amdgcn_mfma_f32_16x16x32_bf16(a, b, acc[c], 0, 0, 0);
        }
    }

#pragma unroll
    for (int c = 0; c < NC; ++c) {
#pragma unroll
        for (int i = 0; i < 4; ++i) {
            int gr = m0 + q * 4 + i;
            if (gr < NN) {
                float v = acc[c][i];
                if constexpr (SCALE) v *= dinv[gr];
                Y[(size_t)gr * NOUT + c * 16 + r] = __float2bfloat16(v);
            }
        }
    }
}

// ---------------------------------------------------------------------------
// Fused: blocks [0, NB_BIN) bin edges by dst>>7 into packed binbuf (FIRST, so
//        the CSR chain's producer isn't stuck in the dispatch tail);
//        blocks [NB_BIN, NB_BIN+NB_G1) do GEMM1 (x@W1 -> Xw, UNscaled).
// Packed entry: (src << 7) | (dst & 127)  — src < 2^17 fits.
// bincnt[b] ends as the bin's total edge count.
// ---------------------------------------------------------------------------
__global__ __launch_bounds__(256) void k_fuseA(const float* __restrict__ X,
                                               const float* __restrict__ W1,
                                               __hip_bfloat16* __restrict__ Xw,
                                               const int* __restrict__ ei32,
                                               int* __restrict__ binbuf,
                                               unsigned* __restrict__ bincnt) {
    __shared__ __align__(16) char smem[32768];  // GEMM WB (32KB) / binning hists (4.7KB)
    const int t = threadIdx.x;

    if (blockIdx.x >= NB_BIN) {
        gemm_body<float, F_IN, F_H, false>(X, W1, nullptr, Xw,
                                           (__hip_bfloat16*)smem,
                                           blockIdx.x - NB_BIN);
        return;
    }

    // ---- binning role ----
    unsigned* hist = (unsigned*)smem;        // [NBINS]
    unsigned* base = hist + NBINS;           // [NBINS]
    unsigned* rank = base + NBINS;           // [NBINS]
    for (int i = t; i < NBINS; i += 256) { hist[i] = 0u; rank[i] = 0u; }
    __syncthreads();

    const bool is64 = ((ei32[1] | ei32[3] | ei32[5] | ei32[7]) == 0);
    const int e0 = blockIdx.x * EPB;
    int pk[8], bin[8];
#pragma unroll
    for (int j = 0; j < 8; ++j) {
        int e = e0 + t + j * 256;
        if (e < NE) {
            int s, d;
            if (is64) {
                const long long* p = (const long long*)ei32;
                s = (int)p[e];
                d = (int)p[NE + e];
            } else {
                s = ei32[e];
                d = ei32[NE + e];
            }
            pk[j]  = (s << BINSHIFT) | (d & 127);
            bin[j] = d >> BINSHIFT;
        } else bin[j] = -1;
    }
#pragma unroll
    for (int j = 0; j < 8; ++j)
        if (bin[j] >= 0) atomicAdd(&hist[bin[j]], 1u);
    __syncthreads();
    for (int b = t; b < NBINS; b += 256)
        base[b] = atomicAdd(&bincnt[b], hist[b]);  // reserve contiguous chunk
    __syncthreads();
#pragma unroll
    for (int j = 0; j < 8; ++j) {
        if (bin[j] >= 0) {
            unsigned rk = atomicAdd(&rank[bin[j]], 1u);
            binbuf[(size_t)bin[j] * CAP + base[bin[j]] + rk] = pk[j];
        }
    }
}

// ---------------------------------------------------------------------------
// Phase B (one block per bin): global base via masked sum of bincnt (inlined
// scan — no separate dispatch), local 128-node histogram, LDS scan ->
// row_ptr + dinv + LDS cursors, then scatter src ids into CSR.
// All atomics LDS; srcs writes confined to this bin's ~8KB region (XCD-local).
// ---------------------------------------------------------------------------
__global__ __launch_bounds__(256) void k_phaseB(const int* __restrict__ binbuf,
                                                const unsigned* __restrict__ bincnt,
                                                unsigned* __restrict__ row_ptr,
                                                float* __restrict__ dinv,
                                                int* __restrict__ srcs) {
    __shared__ unsigned h[128];
    __shared__ unsigned cur[128];
    __shared__ unsigned red[256];
    const int b = blockIdx.x, t = threadIdx.x;

    // base = sum_{i<b} bincnt[i]
    unsigned part = 0;
    for (int i = t; i < NBINS; i += 256)
        if (i < b) part += bincnt[i];
    red[t] = part;
    if (t < 128) h[t] = 0u;
    __syncthreads();
    for (int off = 128; off > 0; off >>= 1) {
        if (t < off) red[t] += red[t + off];
        __syncthreads();
    }
    const unsigned gbase = red[0];

    const unsigned n = bincnt[b];
    const int* buf = binbuf + (size_t)b * CAP;
    for (unsigned i = t; i < n; i += 256)
        atomicAdd(&h[buf[i] & 127], 1u);
    __syncthreads();
    if (t < 128) cur[t] = h[t];
    __syncthreads();
    for (int off = 1; off < 128; off <<= 1) {
        unsigned u = (t < 128 && t >= off) ? cur[t - off] : 0u;
        __syncthreads();
        if (t < 128) cur[t] += u;
        __syncthreads();
    }
    if (t < 128) {
        unsigned ex = gbase + cur[t] - h[t];  // global exclusive prefix
        int node = (b << BINSHIFT) + t;
        if (node < NN) {
            row_ptr[node] = ex;
            dinv[node]    = rsqrtf((float)(h[t] + 1u));  // +1 self-loop
        }
        cur[t] = ex;  // cursor
    }
    if (b == NBINS - 1 && t == 0) row_ptr[NN] = NE;
    __syncthreads();
    for (unsigned i = t; i < n; i += 256) {
        int p = buf[i];
        unsigned pos = atomicAdd(&cur[p & 127], 1u);
        srcs[pos] = p >> BINSHIFT;
    }
}

// ---------------------------------------------------------------------------
// Layer-1 aggregation: one wave per node, 16 lanes x 16B per gathered row,
// 2 independent row-gathers in flight per lane (8 edges per wave-iteration).
// H = relu(dinv[v]*(sum_e dinv[s]*Xw[s] + dinv[v]*Xw[v]) + b1)
// ---------------------------------------------------------------------------
__global__ __launch_bounds__(256) void k_agg1(const __hip_bfloat16* __restrict__ Xw,
                                              const int* __restrict__ srcs,
                                              const unsigned* __restrict__ row_ptr,
                                              const float* __restrict__ dinv,
                                              const float* __restrict__ b1,
                                              __hip_bfloat16* __restrict__ H) {
    const int wv   = (blockIdx.x * 256 + threadIdx.x) >> 6;
    const int lane = threadIdx.x & 63;
    if (wv >= NN) return;
    const int sub = lane >> 4;      // 0..3
    const int fl  = lane & 15;      // feature slice: 8*fl .. 8*fl+7
    const float dn = dinv[wv];

    float acc0[8], acc1[8];
    bf16_8 self = *(const bf16_8*)(Xw + (size_t)wv * F_H + fl * 8);
    const float sw = (sub == 0) ? dn : 0.f;
#pragma unroll
    for (int j = 0; j < 8; ++j) { acc0[j] = sw * (float)self[j]; acc1[j] = 0.f; }

    const unsigned ie = row_ptr[wv + 1];
    unsigned i = row_ptr[wv] + sub;
    for (; i + 4 < ie; i += 8) {   // two groups of 4 edges in flight
        int s0 = srcs[i], s1 = srcs[i + 4];
        float d0 = dinv[s0], d1 = dinv[s1];
        bf16_8 r0 = *(const bf16_8*)(Xw + (size_t)s0 * F_H + fl * 8);
        bf16_8 r1 = *(const bf16_8*)(Xw + (size_t)s1 * F_H + fl * 8);
#pragma unroll
        for (int j = 0; j < 8; ++j) {
            acc0[j] += d0 * (float)r0[j];
            acc1[j] += d1 * (float)r1[j];
        }
    }
    if (i < ie) {
        int s = srcs[i];
        float d = dinv[s];
        bf16_8 r = *(const bf16_8*)(Xw + (size_t)s * F_H + fl * 8);
#pragma unroll
        for (int j = 0; j < 8; ++j) acc0[j] += d * (float)r[j];
    }
#pragma unroll
    for (int j = 0; j < 8; ++j) {
        float a = acc0[j] + acc1[j];
        a += __shfl_xor(a, 16, 64);
        a += __shfl_xor(a, 32, 64);
        acc0[j] = a;
    }
    if (sub == 0) {
        bf16_8 o;
#pragma unroll
        for (int j = 0; j < 8; ++j) {
            float v = fmaxf(dn * acc0[j] + b1[fl * 8 + j], 0.f);
            o[j] = (__bf16)v;
        }
        *(bf16_8*)(H + (size_t)wv * F_H + fl * 8) = o;
    }
}

// Layer 2 GEMM (Hw = dinv * (H1 @ W2)), standalone.
__global__ __launch_bounds__(256) void k_gemm2(const __hip_bfloat16* __restrict__ H1,
                                               const float* __restrict__ W2,
                                               const float* __restrict__ dinv,
                                               __hip_bfloat16* __restrict__ Hw) {
    __shared__ __align__(16) __hip_bfloat16 WB[(F_H / 32) * (F_O / 16) * 512];
    gemm_body<__hip_bfloat16, F_H, F_O, true>(H1, W2, dinv, Hw, WB, blockIdx.x);
}

// ---------------------------------------------------------------------------
// Layer-2 aggregation: one wave per node, 8 lanes x 16B per row, 2 row-gathers
// in flight per lane (16 edges per wave-iteration). Hw pre-scaled by dinv[src].
// out = dinv[v]*(sum_e Hw[s] + Hw[v]) + b2   (f32 output)
// ---------------------------------------------------------------------------
__global__ __launch_bounds__(256) void k_agg2(const __hip_bfloat16* __restrict__ Hw,
                                              const int* __restrict__ srcs,
                                              const unsigned* __restrict__ row_ptr,
                                              const float* __restrict__ dinv,
                                              const float* __restrict__ b2,
                                              float* __restrict__ out) {
    const int wv   = (blockIdx.x * 256 + threadIdx.x) >> 6;
    const int lane = threadIdx.x & 63;
    if (wv >= NN) return;
    const int sub = lane >> 3;      // 0..7
    const int fl  = lane & 7;       // feature slice: 8*fl .. 8*fl+7

    float acc0[8], acc1[8];
    bf16_8 self = *(const bf16_8*)(Hw + (size_t)wv * F_O + fl * 8);
#pragma unroll
    for (int j = 0; j < 8; ++j) {
        acc0[j] = (sub == 0) ? (float)self[j] : 0.f;
        acc1[j] = 0.f;
    }

    const unsigned ie = row_ptr[wv + 1];
    unsigned i = row_ptr[wv] + sub;
    for (; i + 8 < ie; i += 16) {  // two groups of 8 edges in flight
        int s0 = srcs[i], s1 = srcs[i + 8];
        bf16_8 r0 = *(const bf16_8*)(Hw + (size_t)s0 * F_O + fl * 8);
        bf16_8 r1 = *(const bf16_8*)(Hw + (size_t)s1 * F_O + fl * 8);
#pragma unroll
        for (int j = 0; j < 8; ++j) {
            acc0[j] += (float)r0[j];
            acc1[j] += (float)r1[j];
        }
    }
    if (i < ie) {
        int s = srcs[i];
        bf16_8 r = *(const bf16_8*)(Hw + (size_t)s * F_O + fl * 8);
#pragma unroll
        for (int j = 0; j < 8; ++j) acc0[j] += (float)r[j];
    }
#pragma unroll
    for (int j = 0; j < 8; ++j) {
        float a = acc0[j] + acc1[j];
        a += __shfl_xor(a, 8, 64);
        a += __shfl_xor(a, 16, 64);
        a += __shfl_xor(a, 32, 64);
        acc0[j] = a;
    }
    if (sub == 0) {
        float dn = dinv[wv];
        float4 o0 = make_float4(dn * acc0[0] + b2[fl * 8 + 0], dn * acc0[1] + b2[fl * 8 + 1],
                                dn * acc0[2] + b2[fl * 8 + 2], dn * acc0[3] + b2[fl * 8 + 3]);
        float4 o1 = make_float4(dn * acc0[4] + b2[fl * 8 + 4], dn * acc0[5] + b2[fl * 8 + 5],
                                dn * acc0[6] + b2[fl * 8 + 6], dn * acc0[7] + b2[fl * 8 + 7]);
        float4* op = (float4*)(out + (size_t)wv * F_O + fl * 8);
        op[0] = o0;
        op[1] = o1;
    }
}

// ---------------------------------------------------------------------------
extern "C" void kernel_launch(void* const* d_in, const int* in_sizes, int n_in,
                              void* d_out, int out_size, void* d_ws, size_t ws_size,
                              hipStream_t stream) {
    const float* x  = (const float*)d_in[0];
    const int*   ei = (const int*)d_in[1];
    const float* W1 = (const float*)d_in[2];
    const float* b1 = (const float*)d_in[3];
    const float* W2 = (const float*)d_in[4];
    const float* b2 = (const float*)d_in[5];
    float* out = (float*)d_out;

    char* w = (char*)d_ws;
    size_t off = 0;
    auto alloc = [&](size_t bytes) {
        void* p = w + off;
        off += (bytes + 255) & ~(size_t)255;
        return p;
    };
    unsigned* row_ptr = (unsigned*)alloc((size_t)(NN + 1) * 4);
    float*    dinv    = (float*)alloc((size_t)NN * 4);
    unsigned* bincnt  = (unsigned*)alloc((size_t)NBINS * 4);
    int*      srcs    = (int*)alloc((size_t)NE * 4);
    int*      binbuf  = (int*)alloc((size_t)NBINS * CAP * 4);
    __hip_bfloat16* Xw = (__hip_bfloat16*)alloc((size_t)NN * F_H * 2);  // reused as Hw
    __hip_bfloat16* H1 = (__hip_bfloat16*)alloc((size_t)NN * F_H * 2);
    __hip_bfloat16* Hw = Xw;  // alias: Xw dead after k_agg1

    hipMemsetAsync(bincnt, 0, (size_t)NBINS * 4, stream);
    k_fuseA<<<NB_BIN + NB_G1, 256, 0, stream>>>(x, W1, Xw, ei, binbuf, bincnt);
    k_phaseB<<<NBINS, 256, 0, stream>>>(binbuf, bincnt, row_ptr, dinv, srcs);

    k_agg1<<<(NN + 3) / 4, 256, 0, stream>>>(Xw, srcs, row_ptr, dinv, b1, H1);
    k_gemm2<<<(NN + 63) / 64, 256, 0, stream>>>(H1, W2, dinv, Hw);
    k_agg2<<<(NN + 3) / 4, 256, 0, stream>>>(Hw, srcs, row_ptr, dinv, b2, out);
}